// Round 6
// baseline (1607.111 us; speedup 1.0000x reference)
//
#include <hip/hip_runtime.h>
#include <cstddef>

#define SPATIAL (64*64*64)   // 262144 = 1<<18

// ---------------- Stats layout (floats, in ws) ----------------
// accumulators (zeroed each launch):
// 0   : gn_sum[8]     (b*4+g)
// 8   : gn_sumsq[8]
// 16  : in2_sum[16]   (b*8+o)
// 32  : in2_sumsq[16]
// 48  : in3_sum[64]   (b*32+o)
// 112 : in3_sumsq[64]
// derived:
// 176 : gn_a[64]      (b*32+c)
// 240 : gn_shift[64]
// 304 : in2_mu[16]
// 320 : in2_rs[16]
// 336 : in3_mu[64]
// 400 : in3_rs[64]

__device__ __forceinline__ float wave_reduce(float v) {
    #pragma unroll
    for (int off = 32; off; off >>= 1) v += __shfl_down(v, off);
    return v;
}

__global__ void zero_stats(float* __restrict__ stats) {
    if (threadIdx.x < 176) stats[threadIdx.x] = 0.0f;
}

// ================= K1: depthwise conv, one kernel per k =================
// Tile per block: one (b,c) plane, d-tile 8, h-tile 8, w-tile 32.
// LDS input: NS=8+2P slices x R=8+2P rows x 48 cols (stride 48; halo P, zero-fill).
// LDS weights: K*K rows padded to 12 (float4-aligned), broadcast reads in-loop.
// NO global/SMEM access in the hot loop -> no lgkmcnt(0) drains from s_load.
// 256 thr = 4 waves; wave = d-pair; lane = 8r x 8wl; thread = 2d x 4w outputs.
// Window slices slide over zq = j + kd; weight rows slide in a 2-deep reg queue.

template<int K>
__global__ __launch_bounds__(256) void dw_kernel(
    const float* __restrict__ x, const float* __restrict__ wg,
    const float* __restrict__ bg, float* __restrict__ y1, float* __restrict__ stats)
{
    constexpr int P   = K / 2;
    constexpr int G   = (K - 3) / 2;
    constexpr int R   = 8 + 2 * P;      // rows per slice
    constexpr int NS  = 8 + 2 * P;      // slices
    constexpr int CS  = 48;             // col stride
    constexpr int NZQ = K + 1;
    constexpr int NF4 = (4 + 2 * P + 3) / 4;   // float4s per window
    constexpr int NW4 = (K + 3) / 4;           // float4s per weight row

    __shared__ float ls_x[NS * R * CS];
    __shared__ float ls_w[K * K * 12];

    const int gid   = blockIdx.x;          // 2048 = 16 planes * 8 d * 8 h * 2 w
    const int plane = gid >> 7;
    const int sub   = gid & 127;
    const int dc    = sub >> 4;
    const int hq    = (sub >> 1) & 7;
    const int wc    = sub & 1;
    const int b     = plane >> 3, cl = plane & 7;
    const int bc    = (b << 5) + (G << 3) + cl;
    const int d0    = dc << 3, h0 = hq << 3, w0g = wc << 5;

    const float* xin = x + ((size_t)bc << 18);
    const int tid = threadIdx.x;

    // ---- stage weights (padded rows of 12) ----
    for (int i = tid; i < K * K * 12; i += 256) {
        const int kdkh = i / 12;
        const int kw   = i - kdkh * 12;
        ls_w[i] = (kw < K) ? wg[cl * K * K * K + kdkh * K + kw] : 0.0f;
    }
    // ---- stage input slices ----
    for (int s = 0; s < NS; ++s) {
        const int zd  = d0 - P + s;
        const bool dok = (unsigned)zd < 64u;
        float* dst = ls_x + s * (R * CS);
        const float* src = xin + ((size_t)zd << 12);
        for (int i = tid; i < R * CS; i += 256) {
            const int row = i / CS;
            const int col = i - row * CS;
            const int zh = h0 - P + row;
            const int zw = w0g - P + col;
            float v = 0.0f;
            if (dok & ((unsigned)zh < 64u) & ((unsigned)zw < 64u))
                v = src[(zh << 6) + zw];
            dst[i] = v;
        }
    }
    __syncthreads();

    const int lane = tid & 63;
    const int wave = tid >> 6;
    const int r    = lane >> 3;
    const int wl   = lane & 7;
    const int u    = wave << 1;            // d offset of this wave's pair
    const float bias = bg[cl];

    float acc0[4], acc1[4];
    #pragma unroll
    for (int i = 0; i < 4; ++i) { acc0[i] = bias; acc1[i] = bias; }

    #pragma unroll 1
    for (int kh = 0; kh < K; ++kh) {
        const float* lsrow = ls_x + (r + kh) * CS + (wl << 2);
        float wt[2][NW4 * 4];
        #pragma unroll
        for (int zq = 0; zq < NZQ; ++zq) {
            if (zq < K) {   // load weight row kd=zq (broadcast float4s)
                const float* wp = ls_w + (zq * K + kh) * 12;
                #pragma unroll
                for (int q = 0; q < NW4; ++q) {
                    const float4 t = *(const float4*)(wp + 4 * q);
                    wt[zq & 1][4*q+0] = t.x; wt[zq & 1][4*q+1] = t.y;
                    wt[zq & 1][4*q+2] = t.z; wt[zq & 1][4*q+3] = t.w;
                }
            }
            const float* rp = lsrow + (u + zq) * (R * CS);
            float wn[NF4 * 4];
            #pragma unroll
            for (int q = 0; q < NF4; ++q) {
                const float4 t = *(const float4*)(rp + 4 * q);
                wn[4*q+0] = t.x; wn[4*q+1] = t.y; wn[4*q+2] = t.z; wn[4*q+3] = t.w;
            }
            if (zq < K) {       // j=0 output, kd=zq
                #pragma unroll
                for (int kw = 0; kw < K; ++kw) {
                    const float w_ = wt[zq & 1][kw];
                    #pragma unroll
                    for (int i = 0; i < 4; ++i) acc0[i] += wn[kw + i] * w_;
                }
            }
            if (zq >= 1) {      // j=1 output, kd=zq-1
                #pragma unroll
                for (int kw = 0; kw < K; ++kw) {
                    const float w_ = wt[(zq + 1) & 1][kw];
                    #pragma unroll
                    for (int i = 0; i < 4; ++i) acc1[i] += wn[kw + i] * w_;
                }
            }
        }
    }

    // residual + store + stats
    float gsum = 0.0f, gsq = 0.0f;
    {
        const float* cen0 = ls_x + (u + P) * (R * CS) + (r + P) * CS + (wl << 2) + P;
        const float* cen1 = cen0 + (R * CS);
        #pragma unroll
        for (int i = 0; i < 4; ++i) { acc0[i] += cen0[i]; acc1[i] += cen1[i]; }
        const size_t base = ((size_t)bc << 18) + ((size_t)(d0 + u) << 12) +
                            ((size_t)(h0 + r) << 6) + w0g + (wl << 2);
        *(float4*)(y1 + base)          = make_float4(acc0[0], acc0[1], acc0[2], acc0[3]);
        *(float4*)(y1 + base + 4096)   = make_float4(acc1[0], acc1[1], acc1[2], acc1[3]);
        #pragma unroll
        for (int i = 0; i < 4; ++i) {
            gsum += acc0[i] + acc1[i];
            gsq  += acc0[i]*acc0[i] + acc1[i]*acc1[i];
        }
    }
    gsum = wave_reduce(gsum);
    gsq  = wave_reduce(gsq);
    if (lane == 0) {
        atomicAdd(&stats[b * 4 + G], gsum);
        atomicAdd(&stats[8 + b * 4 + G], gsq);
    }
}

// K2: GN finalize -> per-(b,c) affine a, shift
__global__ void gn_finalize(const float* __restrict__ gn_w, const float* __restrict__ gn_b,
                            float* __restrict__ stats)
{
    const int i = threadIdx.x;
    if (i >= 64) return;
    const int b = i >> 5, c = i & 31, g = c >> 3;
    const float N = 8.0f * (float)SPATIAL;
    const float mu  = stats[b * 4 + g] / N;
    const float var = stats[8 + b * 4 + g] / N - mu * mu;
    const float rs  = rsqrtf(var + 1e-5f);
    const float a   = gn_w[c] * rs;
    stats[176 + i] = a;
    stats[240 + i] = gn_b[c] - mu * a;
}

// ============ K3: GN affine + exact GELU + 1x1x1 conv (32->8), float4 ============
__global__ __launch_bounds__(256) void pw_kernel(
    const float* __restrict__ y1, const float* __restrict__ w_pw,
    float* __restrict__ t, float* __restrict__ stats)
{
    const int bid = blockIdx.x;                  // 512 blocks
    const int b   = bid >> 8;
    const int s   = (bid & 255) * 1024 + threadIdx.x * 4;

    const float* yb = y1 + ((size_t)b << 23);
    float acc[8][4] = {};

    for (int cc = 0; cc < 32; cc += 8) {
        float4 yv[8];
        #pragma unroll
        for (int u = 0; u < 8; ++u)
            yv[u] = *(const float4*)(yb + ((size_t)(cc + u) << 18) + s);
        #pragma unroll
        for (int u = 0; u < 8; ++u) {
            const int c = cc + u;
            const float ga = stats[176 + b * 32 + c];   // uniform -> s_load
            const float gs = stats[240 + b * 32 + c];
            float v0 = ga * yv[u].x + gs, v1 = ga * yv[u].y + gs;
            float v2 = ga * yv[u].z + gs, v3 = ga * yv[u].w + gs;
            const float e0 = 0.5f * v0 * (1.0f + erff(v0 * 0.70710678118654752f));
            const float e1 = 0.5f * v1 * (1.0f + erff(v1 * 0.70710678118654752f));
            const float e2 = 0.5f * v2 * (1.0f + erff(v2 * 0.70710678118654752f));
            const float e3 = 0.5f * v3 * (1.0f + erff(v3 * 0.70710678118654752f));
            #pragma unroll
            for (int o = 0; o < 8; ++o) {
                const float wt = w_pw[o * 32 + c];      // uniform -> s_load
                acc[o][0] += e0 * wt; acc[o][1] += e1 * wt;
                acc[o][2] += e2 * wt; acc[o][3] += e3 * wt;
            }
        }
    }

    float* tb = t + ((size_t)b << 21);
    #pragma unroll
    for (int o = 0; o < 8; ++o) {
        *(float4*)(tb + ((size_t)o << 18) + s) =
            make_float4(acc[o][0], acc[o][1], acc[o][2], acc[o][3]);
        float sm = acc[o][0] + acc[o][1] + acc[o][2] + acc[o][3];
        float sq = acc[o][0]*acc[o][0] + acc[o][1]*acc[o][1] +
                   acc[o][2]*acc[o][2] + acc[o][3]*acc[o][3];
        sm = wave_reduce(sm);
        sq = wave_reduce(sq);
        if ((threadIdx.x & 63) == 0) {
            atomicAdd(&stats[16 + b * 8 + o], sm);
            atomicAdd(&stats[32 + b * 8 + o], sq);
        }
    }
}

// K4: IN2 finalize
__global__ void in2_finalize(float* __restrict__ stats)
{
    const int i = threadIdx.x;
    if (i >= 16) return;
    const float N = (float)SPATIAL;
    const float mu  = stats[16 + i] / N;
    const float var = stats[32 + i] / N - mu * mu;
    stats[304 + i] = mu;
    stats[320 + i] = rsqrtf(var + 1e-5f);
}

// ===== K6: 3x3x3 conv (8->32), IN2+SiLU fused into staging, ring over d =====
// Tile: b, d-tile 4, h-tile 8, w-tile 32. LDS in: 8c x 3 slices x 10 rows x 36 cols
// (halo 1; window starts 4-aligned). LDS weights: [c][kd*3+kh][kw][o] f4-broadcast.
#define C3_RS 36
#define C3_ROWSZ (10 * C3_RS)    // 360
#define C3_CH (3 * C3_ROWSZ)     // 1080

__device__ __forceinline__ void c3_stage(const float* __restrict__ tb,
                                         float* __restrict__ ls,
                                         const float* __restrict__ stats,
                                         int b, int zd, int h0, int w0g)
{
    const bool dok = (unsigned)zd < 64u;
    const int slot = (zd + 33) % 3;
    for (int i = threadIdx.x; i < 8 * C3_ROWSZ; i += 256) {
        const int c   = i / C3_ROWSZ;
        const int rem = i - c * C3_ROWSZ;
        const int row = rem / C3_RS;
        const int col = rem - row * C3_RS;
        const int zh  = h0 - 1 + row;
        const int zw  = w0g + col - 1;
        float v = 0.0f;
        if (dok & ((unsigned)zh < 64u) & ((unsigned)zw < 64u) & (col < 34)) {
            const float raw = tb[((size_t)c << 18) + ((size_t)zd << 12) + (zh << 6) + zw];
            const float mu = stats[304 + (b << 3) + c];
            const float rs = stats[320 + (b << 3) + c];
            const float xn = (raw - mu) * rs;
            v = xn / (1.0f + expf(-xn));
        }
        ls[c * C3_CH + slot * C3_ROWSZ + row * C3_RS + col] = v;
    }
}

__global__ __launch_bounds__(256) void conv3_kernel(
    const float* __restrict__ t, const float* __restrict__ w_nxn,
    float* __restrict__ out, float* __restrict__ stats)
{
    __shared__ float ls[8 * C3_CH];       // 8640 dw = 34.6 KB
    __shared__ float lw[8 * 9 * 3 * 32];  // 6912 dw = 27.6 KB  [c][kdh][kw][o]

    const int bid = blockIdx.x;           // 512 blocks
    const int b   = bid >> 8;
    const int r8  = bid & 255;
    const int d0  = (r8 >> 4) << 2;       // 16 d-chunks of 4
    const int h0  = ((r8 >> 1) & 7) << 3; // 8 h-chunks of 8
    const int w0g = (r8 & 1) << 5;        // 2 w-chunks of 32

    const int tid = threadIdx.x;
    // stage weights: lw[((c*9+kdh)*3+kw)*32 + o] = w_nxn[o*216 + c*27 + kdh*3 + kw]
    for (int i = tid; i < 6912; i += 256) {
        const int o    = i & 31;
        const int rest = i >> 5;
        const int kw   = rest % 3;
        const int kdh  = (rest / 3) % 9;
        const int c    = rest / 27;
        lw[i] = w_nxn[o * 216 + c * 27 + kdh * 3 + kw];
    }

    const int w0  = (tid & 7) << 2;       // 0..28
    const int r   = (tid >> 3) & 7;       // 0..7
    const int oq  = __builtin_amdgcn_readfirstlane(tid >> 6);  // wave-uniform
    const int o0  = oq << 3;

    const float* tb = t + ((size_t)b << 21);
    float s3[8] = {}, q3[8] = {};

    c3_stage(tb, ls, stats, b, d0 - 1, h0, w0g);
    c3_stage(tb, ls, stats, b, d0,     h0, w0g);

    for (int d = d0; d < d0 + 4; ++d) {
        c3_stage(tb, ls, stats, b, d + 1, h0, w0g);
        __syncthreads();

        float acc[8][4] = {};
        #pragma unroll 1
        for (int c = 0; c < 8; ++c) {
            const float* lc = ls + c * C3_CH;
            #pragma unroll
            for (int kd = 0; kd < 3; ++kd) {
                const float* sl = lc + ((d + kd + 32) % 3) * C3_ROWSZ;  // zd = d+kd-1
                #pragma unroll
                for (int kh = 0; kh < 3; ++kh) {
                    // window: 2 aligned float4 (need win[0..5], over-read to 8)
                    const float* rowp = sl + (r + kh) * C3_RS + w0;
                    const float4 A = *(const float4*)rowp;
                    const float4 B4 = *(const float4*)(rowp + 4);
                    float wn[8] = {A.x, A.y, A.z, A.w, B4.x, B4.y, B4.z, B4.w};
                    // weights: 6 float4 broadcasts -> wt[kw][oi]
                    const float* wb = lw + ((c * 9 + kd * 3 + kh) * 3) * 32 + o0;
                    float wt[3][8];
                    #pragma unroll
                    for (int kw = 0; kw < 3; ++kw) {
                        const float4 t0 = *(const float4*)(wb + kw * 32);
                        const float4 t1 = *(const float4*)(wb + kw * 32 + 4);
                        wt[kw][0]=t0.x; wt[kw][1]=t0.y; wt[kw][2]=t0.z; wt[kw][3]=t0.w;
                        wt[kw][4]=t1.x; wt[kw][5]=t1.y; wt[kw][6]=t1.z; wt[kw][7]=t1.w;
                    }
                    #pragma unroll
                    for (int oi = 0; oi < 8; ++oi)
                        #pragma unroll
                        for (int kw = 0; kw < 3; ++kw) {
                            const float w_ = wt[kw][oi];
                            #pragma unroll
                            for (int i = 0; i < 4; ++i)
                                acc[oi][i] += wn[kw + i] * w_;
                        }
                }
            }
        }

        #pragma unroll
        for (int oi = 0; oi < 8; ++oi) {
            const int o = o0 + oi;
            *(float4*)(out + ((size_t)((b << 5) + o) << 18) + ((size_t)d << 12) +
                       ((size_t)(h0 + r) << 6) + (w0g + w0)) =
                make_float4(acc[oi][0], acc[oi][1], acc[oi][2], acc[oi][3]);
            s3[oi] += acc[oi][0] + acc[oi][1] + acc[oi][2] + acc[oi][3];
            q3[oi] += acc[oi][0]*acc[oi][0] + acc[oi][1]*acc[oi][1] +
                      acc[oi][2]*acc[oi][2] + acc[oi][3]*acc[oi][3];
        }
        __syncthreads();
    }

    #pragma unroll
    for (int oi = 0; oi < 8; ++oi) {
        float sm = wave_reduce(s3[oi]);
        float sq = wave_reduce(q3[oi]);
        if ((tid & 63) == 0) {
            atomicAdd(&stats[48 + (b << 5) + o0 + oi], sm);
            atomicAdd(&stats[112 + (b << 5) + o0 + oi], sq);
        }
    }
}

// K7: IN3 finalize
__global__ void in3_finalize(float* __restrict__ stats)
{
    const int i = threadIdx.x;
    if (i >= 64) return;
    const float N = (float)SPATIAL;
    const float mu  = stats[48 + i] / N;
    const float var = stats[112 + i] / N - mu * mu;
    stats[336 + i] = mu;
    stats[400 + i] = rsqrtf(var + 1e-5f);
}

// K8: IN3 + SiLU + residual x, in place on d_out (float4)
__global__ __launch_bounds__(256) void final_kernel(
    const float* __restrict__ x, float* __restrict__ out, const float* __restrict__ stats)
{
    const int idx = blockIdx.x * 256 + threadIdx.x;   // 4194304
    const size_t i4 = (size_t)idx << 2;
    const int bc = (int)(i4 >> 18);
    const float mu = stats[336 + bc], rs = stats[400 + bc];
    float4 v = *(const float4*)(out + i4);
    const float4 xr = *(const float4*)(x + i4);
    v.x = (v.x - mu) * rs; v.x = v.x / (1.0f + expf(-v.x)) + xr.x;
    v.y = (v.y - mu) * rs; v.y = v.y / (1.0f + expf(-v.y)) + xr.y;
    v.z = (v.z - mu) * rs; v.z = v.z / (1.0f + expf(-v.z)) + xr.z;
    v.w = (v.w - mu) * rs; v.w = v.w / (1.0f + expf(-v.w)) + xr.w;
    *(float4*)(out + i4) = v;
}

extern "C" void kernel_launch(void* const* d_in, const int* in_sizes, int n_in,
                              void* d_out, int out_size, void* d_ws, size_t ws_size,
                              hipStream_t stream)
{
    const float* x    = (const float*)d_in[0];
    const float* w3   = (const float*)d_in[1];
    const float* b3   = (const float*)d_in[2];
    const float* w5   = (const float*)d_in[3];
    const float* b5   = (const float*)d_in[4];
    const float* w7   = (const float*)d_in[5];
    const float* b7   = (const float*)d_in[6];
    const float* w9   = (const float*)d_in[7];
    const float* b9   = (const float*)d_in[8];
    const float* gn_w = (const float*)d_in[9];
    const float* gn_b = (const float*)d_in[10];
    const float* w_pw = (const float*)d_in[11];
    const float* w_nxn= (const float*)d_in[12];

    char* ws = (char*)d_ws;
    float* t     = (float*)ws;                // 16 MB (2*8*SPATIAL fp32)
    float* stats = (float*)(ws + 16777216);   // 464 floats

    float* out = (float*)d_out;               // y1 scratch, then conv3 output

    zero_stats<<<1, 256, 0, stream>>>(stats);
    dw_kernel<9><<<2048, 256, 0, stream>>>(x, w9, b9, out, stats);
    dw_kernel<7><<<2048, 256, 0, stream>>>(x, w7, b7, out, stats);
    dw_kernel<5><<<2048, 256, 0, stream>>>(x, w5, b5, out, stats);
    dw_kernel<3><<<2048, 256, 0, stream>>>(x, w3, b3, out, stats);
    gn_finalize<<<1, 64, 0, stream>>>(gn_w, gn_b, stats);
    pw_kernel<<<512, 256, 0, stream>>>(out, w_pw, t, stats);
    in2_finalize<<<1, 16, 0, stream>>>(stats);
    conv3_kernel<<<512, 256, 0, stream>>>(t, w_nxn, out, stats);
    in3_finalize<<<1, 64, 0, stream>>>(stats);
    final_kernel<<<16384, 256, 0, stream>>>(x, out, stats);
}